// Round 7
// baseline (576.230 us; speedup 1.0000x reference)
//
#include <hip/hip_runtime.h>

// ---------------- problem constants ----------------
#define Bn 4
#define Sn 2048
#define Dn 1024
#define Hn 16
#define DKn 64
#define DFFn 4096
#define Mn (Bn * Sn) // 8192
#define QKVS 3072    // fused QKV row stride

typedef __bf16 bf16;
typedef __attribute__((ext_vector_type(8))) __bf16 bf16x8;
typedef __attribute__((ext_vector_type(4))) __bf16 bf16x4;
typedef __attribute__((ext_vector_type(8))) unsigned short u16x8;
typedef __attribute__((ext_vector_type(4))) float f32x4;
typedef __attribute__((ext_vector_type(16))) float f32x16;

#define LOG2E_DIV8 0.18033688011112042f  // 0.125 * log2(e)

__device__ __forceinline__ float exp2fast(float x) {
  return __builtin_amdgcn_exp2f(x);
}

// async global->LDS, 16B per lane; LDS dest = wave-uniform base + lane*16
__device__ __forceinline__ void glds16(const bf16* g, bf16* l) {
  __builtin_amdgcn_global_load_lds((const __attribute__((address_space(1))) void*)g,
                                   (__attribute__((address_space(3))) void*)l, 16, 0, 0);
}

__device__ __forceinline__ unsigned int pkbf16(float a, float b) {
  union { __bf16 h[2]; unsigned int u; } x;
  x.h[0] = (__bf16)a; x.h[1] = (__bf16)b;
  return x.u;
}

// ---------------- f32 -> bf16 pack ----------------
__global__ __launch_bounds__(256) void k_cvt_bf16(const float* __restrict__ in,
                                                  bf16* __restrict__ out) {
  size_t i = ((size_t)blockIdx.x * 256 + threadIdx.x) * 8;
  f32x4 a = *(const f32x4*)(in + i);
  f32x4 b = *(const f32x4*)(in + i + 4);
  bf16x8 o;
#pragma unroll
  for (int j = 0; j < 4; ++j) { o[j] = (bf16)a[j]; o[j + 4] = (bf16)b[j]; }
  *(bf16x8*)(out + i) = o;
}

// ---------------- weight transpose: (K,N) f32 -> (N,K) bf16, optional scale ----------------
__global__ __launch_bounds__(256) void k_transpose_bf16(const float* __restrict__ in,
                                                        bf16* __restrict__ out,
                                                        int K, int N, float scale) {
  __shared__ float tile[32][33];
  int n0 = blockIdx.x * 32, k0 = blockIdx.y * 32;
  int tx = threadIdx.x, ty = threadIdx.y;
#pragma unroll
  for (int j = ty; j < 32; j += 8)
    tile[j][tx] = in[(size_t)(k0 + j) * N + n0 + tx];
  __syncthreads();
#pragma unroll
  for (int j = ty; j < 32; j += 8)
    out[(size_t)(n0 + j) * K + k0 + tx] = (bf16)(tile[tx][j] * scale);
}

// ---------------- concat + scale biases for fused QKV ----------------
__global__ __launch_bounds__(256) void k_bias3(const float* __restrict__ bq,
                                               const float* __restrict__ bk,
                                               const float* __restrict__ bv,
                                               float* __restrict__ o) {
  int i = blockIdx.x * 256 + threadIdx.x;
  float v = (i < 1024) ? bq[i] * LOG2E_DIV8
          : (i < 2048) ? bk[i - 1024] : bv[i - 2048];
  o[i] = v;
}

// ---------------- V transpose: v[b*S+s][h*64+dk] (stride vs) -> vT[(bh*64+dk)][s] ----------------
__global__ __launch_bounds__(256) void k_vt(const bf16* __restrict__ v,
                                            bf16* __restrict__ vT, int vs) {
  __shared__ bf16 T[64][72];
  const int t = threadIdx.x;
  const int s0 = blockIdx.x * 64;
  const int bh = blockIdx.y, b = bh >> 4, h = bh & 15;
#pragma unroll
  for (int it = 0; it < 2; ++it) {
    int r = (t >> 3) + it * 32;
    int c = t & 7;
    u16x8 val = *(const u16x8*)(v + (size_t)(b * Sn + s0 + r) * vs + h * 64 + c * 8);
    *(u16x8*)&T[r][c * 8] = val;
  }
  __syncthreads();
#pragma unroll
  for (int it = 0; it < 2; ++it) {
    int d = (t >> 3) + it * 32;
    int cs = t & 7;
    bf16x8 o;
#pragma unroll
    for (int j = 0; j < 8; ++j) o[j] = T[cs * 8 + j][d];
    *(bf16x8*)(vT + ((size_t)bh * 64 + d) * Sn + s0 + cs * 8) = o;
  }
}

// ---------------- staging part Q of one K-tile (BN fixed 256) ----------------
template <int BM, int Q>
__device__ __forceinline__ void stage_part(const bf16* __restrict__ A,
                                           const bf16* __restrict__ BT,
                                           bf16* As, bf16* Bs, int m0, int n0,
                                           int Kdim, int t, int wid, int lr, int lc) {
  if constexpr (BM == 256) {
    int r = Q * 64 + wid * 8 + lr;
    int ch = lc ^ (r & 7);
    glds16(A + (size_t)(m0 + r) * Kdim + (size_t)t * 64 + ch * 8,
           As + (Q * 64 + wid * 8) * 64);
    glds16(BT + (size_t)(n0 + r) * Kdim + (size_t)t * 64 + ch * 8,
           Bs + (Q * 64 + wid * 8) * 64);
  } else {
    if constexpr (Q < 2) {
      int r = Q * 64 + wid * 8 + lr;
      int ch = lc ^ (r & 7);
      glds16(A + (size_t)(m0 + r) * Kdim + (size_t)t * 64 + ch * 8,
             As + (Q * 64 + wid * 8) * 64);
      glds16(BT + (size_t)(n0 + r) * Kdim + (size_t)t * 64 + ch * 8,
             Bs + (Q * 64 + wid * 8) * 64);
    } else if constexpr (Q == 2) {
      int r2 = 128 + wid * 8 + lr;
      int ch2 = lc ^ (r2 & 7);
      glds16(BT + (size_t)(n0 + r2) * Kdim + (size_t)t * 64 + ch2 * 8,
             Bs + (128 + wid * 8) * 64);
      int r3 = 192 + wid * 8 + lr;
      int ch3 = lc ^ (r3 & 7);
      glds16(BT + (size_t)(n0 + r3) * Kdim + (size_t)t * 64 + ch3 * 8,
             Bs + (192 + wid * 8) * 64);
    }
  }
}

// ---------------- phased MFMA GEMM: BMx256 tile, BK=64, 8 waves, 4 phases/K-tile ----------------
// wave (wm,wn): rows wm*(BM/2)+[0,BM/2), cols wn*64+[0,64). Counted vmcnt(2) at phase0 only.
template <int BM, int DO_RELU>
__global__ __launch_bounds__(512, 2) void k_gemm8p(const bf16* __restrict__ A,
                                                   const bf16* __restrict__ BT,
                                                   const float* __restrict__ bias,
                                                   bf16* __restrict__ C,
                                                   int Ndim, int Kdim) {
  constexpr int MF = BM / 32;   // A-frags per wave (8 or 4)
  constexpr int MFH = MF / 2;   // per phase-half
  __shared__ __align__(128) bf16 Asm[2][BM * 64];
  __shared__ __align__(128) bf16 Bsm[2][256 * 64];
  const int tid = threadIdx.x;
  const int wid = tid >> 6, lane = tid & 63;
  const int l15 = lane & 15, l4 = lane >> 4;
  const int wm = wid >> 2, wn = wid & 3;

  // XCD-chunked swizzle (all grids %8 == 0)
  const int gx = gridDim.x;
  int lin = blockIdx.y * gx + blockIdx.x;
  const int nwg = gx * gridDim.y;
  lin = (lin & 7) * (nwg >> 3) + (lin >> 3);
  const int m0 = (lin / gx) * BM;
  const int n0 = (lin % gx) * 256;

  f32x4 acc[MF][4];
#pragma unroll
  for (int mf = 0; mf < MF; ++mf)
#pragma unroll
    for (int nf = 0; nf < 4; ++nf) acc[mf][nf] = f32x4{0.f, 0.f, 0.f, 0.f};

  const int lr = lane >> 3, lc = lane & 7;
  const int NT = Kdim >> 6;

  bf16x8 af[MFH][2], bfA[2][2], bfB[2][2];

  int p = 0;
  stage_part<BM, 0>(A, BT, &Asm[0][0], &Bsm[0][0], m0, n0, Kdim, 0, wid, lr, lc);
  stage_part<BM, 1>(A, BT, &Asm[0][0], &Bsm[0][0], m0, n0, Kdim, 0, wid, lr, lc);
  stage_part<BM, 2>(A, BT, &Asm[0][0], &Bsm[0][0], m0, n0, Kdim, 0, wid, lr, lc);
  stage_part<BM, 3>(A, BT, &Asm[0][0], &Bsm[0][0], m0, n0, Kdim, 0, wid, lr, lc);

  for (int t = 0; t < NT; ++t) {
    bf16* Acur = &Asm[p][0];
    bf16* Bcur = &Bsm[p][0];
    bf16* Anxt = &Asm[p ^ 1][0];
    bf16* Bnxt = &Bsm[p ^ 1][0];
    const bool pf = (t + 1 < NT);

    // ---- phase 0: stage p0 | vmcnt gate | reads A-low + B-low | MFMA ----
    if (pf) {
      stage_part<BM, 0>(A, BT, Anxt, Bnxt, m0, n0, Kdim, t + 1, wid, lr, lc);
      asm volatile("s_waitcnt vmcnt(2)" ::: "memory");
    } else {
      asm volatile("s_waitcnt vmcnt(0)" ::: "memory");
    }
    __builtin_amdgcn_sched_barrier(0);
    __builtin_amdgcn_s_barrier();
#pragma unroll
    for (int mf = 0; mf < MFH; ++mf)
#pragma unroll
      for (int kk = 0; kk < 2; ++kk) {
        int row = wm * (BM / 2) + mf * 16 + l15;
        int ch = (kk * 4 + l4) ^ (row & 7);
        af[mf][kk] = *(const bf16x8*)&Acur[row * 64 + ch * 8];
      }
#pragma unroll
    for (int nf = 0; nf < 2; ++nf)
#pragma unroll
      for (int kk = 0; kk < 2; ++kk) {
        int row = wn * 64 + nf * 16 + l15;
        int ch = (kk * 4 + l4) ^ (row & 7);
        bfA[nf][kk] = *(const bf16x8*)&Bcur[row * 64 + ch * 8];
      }
    __builtin_amdgcn_s_setprio(1);
#pragma unroll
    for (int mf = 0; mf < MFH; ++mf)
#pragma unroll
      for (int nf = 0; nf < 2; ++nf)
#pragma unroll
        for (int kk = 0; kk < 2; ++kk)
          acc[mf][nf] = __builtin_amdgcn_mfma_f32_16x16x32_bf16(af[mf][kk], bfA[nf][kk],
                                                                acc[mf][nf], 0, 0, 0);
    __builtin_amdgcn_s_setprio(0);
    __builtin_amdgcn_s_barrier();

    // ---- phase 1: stage p1 | reads B-high | MFMA A-low x B-high ----
    if (pf) stage_part<BM, 1>(A, BT, Anxt, Bnxt, m0, n0, Kdim, t + 1, wid, lr, lc);
#pragma unroll
    for (int nf = 0; nf < 2; ++nf)
#pragma unroll
      for (int kk = 0; kk < 2; ++kk) {
        int row = wn * 64 + (2 + nf) * 16 + l15;
        int ch = (kk * 4 + l4) ^ (row & 7);
        bfB[nf][kk] = *(const bf16x8*)&Bcur[row * 64 + ch * 8];
      }
    __builtin_amdgcn_s_barrier();
    __builtin_amdgcn_s_setprio(1);
#pragma unroll
    for (int mf = 0; mf < MFH; ++mf)
#pragma unroll
      for (int nf = 0; nf < 2; ++nf)
#pragma unroll
        for (int kk = 0; kk < 2; ++kk)
          acc[mf][2 + nf] = __builtin_amdgcn_mfma_f32_16x16x32_bf16(af[mf][kk], bfB[nf][kk],
                                                                    acc[mf][2 + nf], 0, 0, 0);
    __builtin_amdgcn_s_setprio(0);
    __builtin_amdgcn_s_barrier();

    // ---- phase 2: stage p2 | reads A-high | MFMA A-high x B-high ----
    if (pf) stage_part<BM, 2>(A, BT, Anxt, Bnxt, m0, n0, Kdim, t + 1, wid, lr, lc);
#pragma unroll
    for (int mf = 0; mf < MFH; ++mf)
#pragma unroll
      for (int kk = 0; kk < 2; ++kk) {
        int row = wm * (BM / 2) + (MFH + mf) * 16 + l15;
        int ch = (kk * 4 + l4) ^ (row & 7);
        af[mf][kk] = *(const bf16x8*)&Acur[row * 64 + ch * 8];
      }
    __builtin_amdgcn_s_barrier();
    __builtin_amdgcn_s_setprio(1);
#pragma unroll
    for (int mf = 0; mf < MFH; ++mf)
#pragma unroll
      for (int nf = 0; nf < 2; ++nf)
#pragma unroll
        for (int kk = 0; kk < 2; ++kk)
          acc[MFH + mf][2 + nf] = __builtin_amdgcn_mfma_f32_16x16x32_bf16(
              af[mf][kk], bfB[nf][kk], acc[MFH + mf][2 + nf], 0, 0, 0);
    __builtin_amdgcn_s_setprio(0);
    __builtin_amdgcn_s_barrier();

    // ---- phase 3: stage p3 | reads B-low | MFMA A-high x B-low ----
    if (pf) stage_part<BM, 3>(A, BT, Anxt, Bnxt, m0, n0, Kdim, t + 1, wid, lr, lc);
#pragma unroll
    for (int nf = 0; nf < 2; ++nf)
#pragma unroll
      for (int kk = 0; kk < 2; ++kk) {
        int row = wn * 64 + nf * 16 + l15;
        int ch = (kk * 4 + l4) ^ (row & 7);
        bfA[nf][kk] = *(const bf16x8*)&Bcur[row * 64 + ch * 8];
      }
    __builtin_amdgcn_s_barrier();
    __builtin_amdgcn_s_setprio(1);
#pragma unroll
    for (int mf = 0; mf < MFH; ++mf)
#pragma unroll
      for (int nf = 0; nf < 2; ++nf)
#pragma unroll
        for (int kk = 0; kk < 2; ++kk)
          acc[MFH + mf][nf] = __builtin_amdgcn_mfma_f32_16x16x32_bf16(
              af[mf][kk], bfA[nf][kk], acc[MFH + mf][nf], 0, 0, 0);
    __builtin_amdgcn_s_setprio(0);
    __builtin_amdgcn_s_barrier();
    p ^= 1;
  }

  // epilogue
#pragma unroll
  for (int mf = 0; mf < MF; ++mf)
#pragma unroll
    for (int nf = 0; nf < 4; ++nf) {
      int c = n0 + wn * 64 + nf * 16 + l15;
      float bv = bias[c];
      int r0 = m0 + wm * (BM / 2) + mf * 16 + l4 * 4;
#pragma unroll
      for (int r = 0; r < 4; ++r) {
        float val = acc[mf][nf][r] + bv;
        if (DO_RELU) val = fmaxf(val, 0.f);
        C[(size_t)(r0 + r) * Ndim + c] = (bf16)val;
      }
    }
}

// ---------------- flash attention, swapped-operand 32x32 MFMA ----------------
__global__ __launch_bounds__(256) void k_attn(const bf16* __restrict__ q,
                                              const bf16* __restrict__ k,
                                              const bf16* __restrict__ vT,
                                              const int* __restrict__ mask,
                                              bf16* __restrict__ ctx, int qs) {
  __shared__ __align__(128) bf16 Kt[2][64 * 64];
  __shared__ __align__(128) bf16 Vt[2][64 * 64];
  __shared__ float Mb[Sn];
  const int tid = threadIdx.x, wid = tid >> 6, lane = tid & 63;
  const int q31 = lane & 31, hi = lane >> 5;

  int lin = blockIdx.y * gridDim.x + blockIdx.x;  // 1024 blocks
  lin = (lin & 7) * 128 + (lin >> 3);
  const int qblk = lin & 15, bh = lin >> 4;
  const int b = bh >> 4, h = bh & 15;
  const int q0 = qblk * 128 + wid * 32;

  for (int i = tid; i < Sn; i += 256)
    Mb[i] = mask[b * Sn + i] ? 0.f : -1.44269504e9f;

  bf16x8 qf[4];
#pragma unroll
  for (int t = 0; t < 4; ++t)
    qf[t] = *(const bf16x8*)(q + (size_t)(b * Sn + q0 + q31) * qs + h * 64 +
                             t * 16 + hi * 8);

  f32x16 o[2];
  o[0] = {}; o[1] = {};
  float mr = -INFINITY, lr = 0.f;

  const int lrow = lane >> 3;
  const int lch0 = lane & 7;

  for (int kb = 0; kb < Sn / 64; ++kb) {
    const int cur = kb & 1;
    if (kb == 0) {
#pragma unroll
      for (int s = 0; s < 2; ++s) {
        int row = (wid + 4 * s) * 8 + lrow;
        int ch = lch0 ^ (lrow ^ ((wid + 4 * s) & 3));
        glds16(k + (size_t)(b * Sn + row) * qs + h * 64 + ch * 8,
               &Kt[0][(wid + 4 * s) * 512]);
        glds16(vT + ((size_t)bh * 64 + row) * Sn + ch * 8,
               &Vt[0][(wid + 4 * s) * 512]);
      }
      __syncthreads();
    }
    if (kb + 1 < Sn / 64) {
#pragma unroll
      for (int s = 0; s < 2; ++s) {
        int row = (wid + 4 * s) * 8 + lrow;
        int ch = lch0 ^ (lrow ^ ((wid + 4 * s) & 3));
        glds16(k + (size_t)(b * Sn + (kb + 1) * 64 + row) * qs + h * 64 + ch * 8,
               &Kt[cur ^ 1][(wid + 4 * s) * 512]);
        glds16(vT + ((size_t)bh * 64 + row) * Sn + (kb + 1) * 64 + ch * 8,
               &Vt[cur ^ 1][(wid + 4 * s) * 512]);
      }
    }

    // S^T = K . Q^T with C initialized to the additive mask bias
    f32x16 sc[2];
#pragma unroll
    for (int kf = 0; kf < 2; ++kf)
#pragma unroll
      for (int rg = 0; rg < 4; ++rg) {
        f32x4 mb4 = *(const f32x4*)&Mb[kb * 64 + kf * 32 + rg * 8 + 4 * hi];
#pragma unroll
        for (int j = 0; j < 4; ++j) sc[kf][rg * 4 + j] = mb4[j];
      }
#pragma unroll
    for (int t = 0; t < 4; ++t) {
#pragma unroll
      for (int kf = 0; kf < 2; ++kf) {
        int row = kf * 32 + q31;
        int ch = (t * 2 + hi) ^ ((row & 7) ^ ((row >> 3) & 3));
        bf16x8 kfr = *(const bf16x8*)&Kt[cur][row * 64 + ch * 8];
        sc[kf] = __builtin_amdgcn_mfma_f32_32x32x16_bf16(kfr, qf[t], sc[kf], 0, 0, 0);
      }
    }

    // row max: max3-friendly tree + half exchange
    float rmax = fmaxf(sc[0][0], sc[0][1]);
#pragma unroll
    for (int i = 2; i < 16; i += 2)
      rmax = fmaxf(fmaxf(rmax, sc[0][i]), sc[0][i + 1]);
#pragma unroll
    for (int i = 0; i < 16; i += 2)
      rmax = fmaxf(fmaxf(rmax, sc[1][i]), sc[1][i + 1]);
    rmax = fmaxf(rmax, __shfl_xor(rmax, 32));

    if (!__all(rmax <= mr + 8.f)) {
      float mnew = fmaxf(mr, rmax);
      float psc = exp2fast(mr - mnew);
      mr = mnew;
      lr *= psc;
#pragma unroll
      for (int af = 0; af < 2; ++af)
#pragma unroll
        for (int i = 0; i < 16; ++i) o[af][i] *= psc;
    }

    float psum = 0.f;
#pragma unroll
    for (int kf = 0; kf < 2; ++kf)
#pragma unroll
      for (int i = 0; i < 16; ++i) {
        float p = exp2fast(sc[kf][i] - mr);
        sc[kf][i] = p;
        psum += p;
      }
    psum += __shfl_xor(psum, 32);
    lr += psum;

#pragma unroll
    for (int ks = 0; ks < 4; ++ks) {
      const int kf = ks >> 1, R = (ks & 1) * 8;
      unsigned int a0 = pkbf16(sc[kf][R + 0], sc[kf][R + 1]);
      unsigned int a1 = pkbf16(sc[kf][R + 2], sc[kf][R + 3]);
      unsigned int b0 = pkbf16(sc[kf][R + 4], sc[kf][R + 5]);
      unsigned int b1 = pkbf16(sc[kf][R + 6], sc[kf][R + 7]);
      unsigned int sxa0 = __shfl_xor(a0, 32), sxa1 = __shfl_xor(a1, 32);
      unsigned int sxb0 = __shfl_xor(b0, 32), sxb1 = __shfl_xor(b1, 32);
      union { unsigned int w[4]; bf16x8 v; } pfu;
      pfu.w[0] = hi ? sxb0 : a0;
      pfu.w[1] = hi ? sxb1 : a1;
      pfu.w[2] = hi ? b0 : sxa0;
      pfu.w[3] = hi ? b1 : sxa1;
#pragma unroll
      for (int af = 0; af < 2; ++af) {
        int row = af * 32 + q31;
        int ch = (ks * 2 + hi) ^ ((row & 7) ^ ((row >> 3) & 3));
        bf16x8 vfr = *(const bf16x8*)&Vt[cur][row * 64 + ch * 8];
        o[af] = __builtin_amdgcn_mfma_f32_32x32x16_bf16(vfr, pfu.v, o[af], 0, 0, 0);
      }
    }
    __syncthreads();
  }

  float inv = 1.f / lr;
  const size_t cbase = (size_t)(b * Sn + q0 + q31) * Dn + h * 64;
#pragma unroll
  for (int af = 0; af < 2; ++af)
#pragma unroll
    for (int rg = 0; rg < 4; ++rg) {
      bf16x4 ov;
#pragma unroll
      for (int j = 0; j < 4; ++j) ov[j] = (bf16)(o[af][rg * 4 + j] * inv);
      *(bf16x4*)(ctx + cbase + af * 32 + rg * 8 + 4 * hi) = ov;
    }
}

// ---------------- residual + LayerNorm (ddof=1, /(std+eps)) ----------------
template <int XF32, int OUTF32>
__global__ __launch_bounds__(256) void k_ln(const void* __restrict__ xp,
                                            const bf16* __restrict__ res,
                                            const float* __restrict__ gamma,
                                            const float* __restrict__ beta,
                                            void* __restrict__ yout) {
  const int row = blockIdx.x, t = threadIdx.x;
  const size_t base = (size_t)row * Dn + t * 4;
  f32x4 a;
  if constexpr (XF32) {
    a = *(const f32x4*)((const float*)xp + base);
  } else {
    bf16x4 x4 = *(const bf16x4*)((const bf16*)xp + base);
#pragma unroll
    for (int j = 0; j < 4; ++j) a[j] = (float)x4[j];
  }
  bf16x4 rb = *(const bf16x4*)(res + base);
  f32x4 vv;
#pragma unroll
  for (int j = 0; j < 4; ++j) vv[j] = a[j] + (float)rb[j];

  float s = vv[0] + vv[1] + vv[2] + vv[3];
#pragma unroll
  for (int off = 32; off; off >>= 1) s += __shfl_xor(s, off);
  __shared__ float red1[4], red2[4];
  if ((t & 63) == 0) red1[t >> 6] = s;
  __syncthreads();
  float mean = (red1[0] + red1[1] + red1[2] + red1[3]) * (1.f / 1024.f);

  float d[4], s2 = 0.f;
#pragma unroll
  for (int j = 0; j < 4; ++j) { d[j] = vv[j] - mean; s2 += d[j] * d[j]; }
#pragma unroll
  for (int off = 32; off; off >>= 1) s2 += __shfl_xor(s2, off);
  if ((t & 63) == 0) red2[t >> 6] = s2;
  __syncthreads();
  float var = (red2[0] + red2[1] + red2[2] + red2[3]) * (1.f / 1023.f);
  float inv = 1.f / (sqrtf(var) + 1e-6f);

  f32x4 g = *(const f32x4*)(gamma + t * 4);
  f32x4 bt = *(const f32x4*)(beta + t * 4);
#pragma unroll
  for (int j = 0; j < 4; ++j) d[j] = g[j] * d[j] * inv + bt[j];
  if constexpr (OUTF32) {
    f32x4 outv = {d[0], d[1], d[2], d[3]};
    *(f32x4*)((float*)yout + base) = outv;
  } else {
    bf16x4 outb;
#pragma unroll
    for (int j = 0; j < 4; ++j) outb[j] = (bf16)d[j];
    *(bf16x4*)((bf16*)yout + base) = outb;
  }
}

// ---------------- host launcher ----------------
extern "C" void kernel_launch(void* const* d_in, const int* in_sizes, int n_in,
                              void* d_out, int out_size, void* d_ws, size_t ws_size,
                              hipStream_t stream) {
  const float* x   = (const float*)d_in[0];
  const int*   msk = (const int*)d_in[1];
  const float* Wq  = (const float*)d_in[2];
  const float* bq  = (const float*)d_in[3];
  const float* Wk  = (const float*)d_in[4];
  const float* bk  = (const float*)d_in[5];
  const float* Wv  = (const float*)d_in[6];
  const float* bv  = (const float*)d_in[7];
  const float* Wo  = (const float*)d_in[8];
  const float* bo  = (const float*)d_in[9];
  const float* W1  = (const float*)d_in[10];
  const float* b1  = (const float*)d_in[11];
  const float* W2  = (const float*)d_in[12];
  const float* b2  = (const float*)d_in[13];
  const float* g1  = (const float*)d_in[14];
  const float* be1 = (const float*)d_in[15];
  const float* g2  = (const float*)d_in[16];
  const float* be2 = (const float*)d_in[17];
  float* out = (float*)d_out;

  char* w = (char*)d_ws;
  size_t off = 0;
  auto alloc = [&](size_t bytes) { void* p = w + off; off += (bytes + 255) & ~(size_t)255; return p; };
  bf16* xb    = (bf16*)alloc((size_t)Mn * Dn * 2);        // 16MB; dead after QKV -> vT overlay
  bf16* wqkvT = (bf16*)alloc((size_t)QKVS * Dn * 2);      // 6MB
  bf16* woT   = (bf16*)alloc((size_t)Dn * Dn * 2);        // 2MB
  bf16* w1T   = (bf16*)alloc((size_t)Dn * DFFn * 2);      // 8MB
  bf16* w2T   = (bf16*)alloc((size_t)DFFn * Dn * 2);      // 8MB
  float* bqkv = (float*)alloc((size_t)QKVS * 4);
  bf16* qkv   = (bf16*)alloc((size_t)Mn * QKVS * 2);      // 48MB; dead after attn -> hh
  bf16* ctx   = (bf16*)alloc((size_t)Mn * Dn * 2);        // 16MB; dead after Wo
  bf16* attnb = (bf16*)alloc((size_t)Mn * Dn * 2);        // 16MB; Wo out, dead after LN1
  bf16* yb    = (bf16*)alloc((size_t)Mn * Dn * 2);        // 16MB (residual stream, bf16)
  (void)ws_size; (void)in_sizes; (void)n_in; (void)out_size;
  // overlays (regions dead by the time these are written):
  bf16* vT = xb;          // attn V^T; xb dead after QKV GEMM
  bf16* hh = qkv;         // FF1 out 64MB: spans qkv(48) + ctx(16), both dead
  bf16* ff = xb;          // FF2 out 16MB: xb/vT dead after attn

  // 1. pack x, transpose weights (Wq pre-scaled for exp2-domain softmax), biases
  k_cvt_bf16<<<(Mn * Dn) / 2048, 256, 0, stream>>>(x, xb);
  dim3 tb(32, 8);
  k_transpose_bf16<<<dim3(32, 32), tb, 0, stream>>>(Wq, wqkvT, Dn, Dn, LOG2E_DIV8);
  k_transpose_bf16<<<dim3(32, 32), tb, 0, stream>>>(Wk, wqkvT + (size_t)1024 * Dn, Dn, Dn, 1.f);
  k_transpose_bf16<<<dim3(32, 32), tb, 0, stream>>>(Wv, wqkvT + (size_t)2048 * Dn, Dn, Dn, 1.f);
  k_transpose_bf16<<<dim3(32, 32), tb, 0, stream>>>(Wo, woT, Dn, Dn, 1.f);
  k_transpose_bf16<<<dim3(128, 32), tb, 0, stream>>>(W1, w1T, Dn, DFFn, 1.f);
  k_transpose_bf16<<<dim3(32, 128), tb, 0, stream>>>(W2, w2T, DFFn, Dn, 1.f);
  k_bias3<<<QKVS / 256, 256, 0, stream>>>(bq, bk, bv, bqkv);

  // 2. fused QKV projection: qkv[8192][3072]
  k_gemm8p<256, 0><<<dim3(QKVS / 256, Mn / 256), 512, 0, stream>>>(xb, wqkvT, bqkv, qkv, QKVS, Dn);

  // 3. V transpose + flash attention
  k_vt<<<dim3(Sn / 64, Bn * Hn), 256, 0, stream>>>(qkv + 2048, vT, QKVS);
  k_attn<<<dim3(Sn / 128, Bn * Hn), 256, 0, stream>>>(qkv, qkv + 1024, vT, msk, ctx, QKVS);

  // 4. output projection (BM=128 -> 256 blocks)
  k_gemm8p<128, 0><<<dim3(Dn / 256, Mn / 128), 512, 0, stream>>>(ctx, woT, bo, attnb, Dn, Dn);

  // 5. LN1: yb = LN(x + attnb), bf16 out only
  k_ln<1, 0><<<Mn, 256, 0, stream>>>(x, attnb, g1, be1, yb);

  // 6. FF1 (relu)
  k_gemm8p<256, 1><<<dim3(DFFn / 256, Mn / 256), 512, 0, stream>>>(yb, w1T, b1, hh, DFFn, Dn);

  // 7. FF2
  k_gemm8p<128, 0><<<dim3(Dn / 256, Mn / 128), 512, 0, stream>>>(hh, w2T, b2, ff, Dn, DFFn);

  // 8. LN2: out = LN(yb + ff), f32 out
  k_ln<0, 1><<<Mn, 256, 0, stream>>>(yb, ff, g2, be2, out);
}

// Round 8
// 457.324 us; speedup vs baseline: 1.2600x; 1.2600x over previous
//
#include <hip/hip_runtime.h>

// ---------------- problem constants ----------------
#define Bn 4
#define Sn 2048
#define Dn 1024
#define Hn 16
#define DKn 64
#define DFFn 4096
#define Mn (Bn * Sn) // 8192
#define QKVS 3072    // fused QKV row stride

typedef __bf16 bf16;
typedef __attribute__((ext_vector_type(8))) __bf16 bf16x8;
typedef __attribute__((ext_vector_type(4))) __bf16 bf16x4;
typedef __attribute__((ext_vector_type(8))) unsigned short u16x8;
typedef __attribute__((ext_vector_type(4))) float f32x4;
typedef __attribute__((ext_vector_type(16))) float f32x16;

#define LOG2E_DIV8 0.18033688011112042f  // 0.125 * log2(e)

__device__ __forceinline__ float exp2fast(float x) {
  return __builtin_amdgcn_exp2f(x);
}

// async global->LDS, 16B per lane; LDS dest = wave-uniform base + lane*16
__device__ __forceinline__ void glds16(const bf16* g, bf16* l) {
  __builtin_amdgcn_global_load_lds((const __attribute__((address_space(1))) void*)g,
                                   (__attribute__((address_space(3))) void*)l, 16, 0, 0);
}

__device__ __forceinline__ unsigned int pkbf16(float a, float b) {
  union { __bf16 h[2]; unsigned int u; } x;
  x.h[0] = (__bf16)a; x.h[1] = (__bf16)b;
  return x.u;
}

// ---------------- f32 -> bf16 pack ----------------
__global__ __launch_bounds__(256) void k_cvt_bf16(const float* __restrict__ in,
                                                  bf16* __restrict__ out) {
  size_t i = ((size_t)blockIdx.x * 256 + threadIdx.x) * 8;
  f32x4 a = *(const f32x4*)(in + i);
  f32x4 b = *(const f32x4*)(in + i + 4);
  bf16x8 o;
#pragma unroll
  for (int j = 0; j < 4; ++j) { o[j] = (bf16)a[j]; o[j + 4] = (bf16)b[j]; }
  *(bf16x8*)(out + i) = o;
}

// ---------------- weight transpose: (K,N) f32 -> (N,K) bf16, optional scale ----------------
__global__ __launch_bounds__(256) void k_transpose_bf16(const float* __restrict__ in,
                                                        bf16* __restrict__ out,
                                                        int K, int N, float scale) {
  __shared__ float tile[32][33];
  int n0 = blockIdx.x * 32, k0 = blockIdx.y * 32;
  int tx = threadIdx.x, ty = threadIdx.y;
#pragma unroll
  for (int j = ty; j < 32; j += 8)
    tile[j][tx] = in[(size_t)(k0 + j) * N + n0 + tx];
  __syncthreads();
#pragma unroll
  for (int j = ty; j < 32; j += 8)
    out[(size_t)(n0 + j) * K + k0 + tx] = (bf16)(tile[tx][j] * scale);
}

// ---------------- concat + scale biases for fused QKV ----------------
__global__ __launch_bounds__(256) void k_bias3(const float* __restrict__ bq,
                                               const float* __restrict__ bk,
                                               const float* __restrict__ bv,
                                               float* __restrict__ o) {
  int i = blockIdx.x * 256 + threadIdx.x;
  float v = (i < 1024) ? bq[i] * LOG2E_DIV8
          : (i < 2048) ? bk[i - 1024] : bv[i - 2048];
  o[i] = v;
}

// ---------------- V transpose: v[b*S+s][h*64+dk] (stride vs) -> vT[(bh*64+dk)][s] ----------------
__global__ __launch_bounds__(256) void k_vt(const bf16* __restrict__ v,
                                            bf16* __restrict__ vT, int vs) {
  __shared__ bf16 T[64][72];
  const int t = threadIdx.x;
  const int s0 = blockIdx.x * 64;
  const int bh = blockIdx.y, b = bh >> 4, h = bh & 15;
#pragma unroll
  for (int it = 0; it < 2; ++it) {
    int r = (t >> 3) + it * 32;
    int c = t & 7;
    u16x8 val = *(const u16x8*)(v + (size_t)(b * Sn + s0 + r) * vs + h * 64 + c * 8);
    *(u16x8*)&T[r][c * 8] = val;
  }
  __syncthreads();
#pragma unroll
  for (int it = 0; it < 2; ++it) {
    int d = (t >> 3) + it * 32;
    int cs = t & 7;
    bf16x8 o;
#pragma unroll
    for (int j = 0; j < 8; ++j) o[j] = T[cs * 8 + j][d];
    *(bf16x8*)(vT + ((size_t)bh * 64 + d) * Sn + s0 + cs * 8) = o;
  }
}

// ---------------- 256-row MFMA GEMM, 8 waves, counted-vmcnt 2-deep pipeline (R5-verified) ----------------
template <int NFRAG, int DO_RELU>
__global__ __launch_bounds__(512, 2) void k_gemm256(const bf16* __restrict__ A,
                                                    const bf16* __restrict__ BT,
                                                    const float* __restrict__ bias,
                                                    bf16* __restrict__ C,
                                                    int Ndim, int Kdim) {
  __shared__ __align__(128) bf16 Asm[2][256 * 64];
  __shared__ __align__(128) bf16 Bsm[2][NFRAG * 64 * 64];
  const int tid = threadIdx.x;
  const int wid = tid >> 6, lane = tid & 63;
  const int l15 = lane & 15, l4 = lane >> 4;
  const int wm = wid >> 2, wn = wid & 3;

  // XCD-chunked swizzle (all grids here have nwg % 8 == 0)
  const int gx = gridDim.x;
  int lin = blockIdx.y * gx + blockIdx.x;
  const int nwg = gx * gridDim.y;
  lin = (lin & 7) * (nwg >> 3) + (lin >> 3);
  const int m0 = (lin / gx) * 256;
  const int n0 = (lin % gx) * (NFRAG * 64);

  f32x4 acc[8][NFRAG];
#pragma unroll
  for (int mf = 0; mf < 8; ++mf)
#pragma unroll
    for (int nf = 0; nf < NFRAG; ++nf) acc[mf][nf] = f32x4{0.f, 0.f, 0.f, 0.f};

  const int lr = lane >> 3, lc = lane & 7;
  const int NT = Kdim >> 6;

#define STAGE(buf, t)                                                              \
  {                                                                                \
    _Pragma("unroll") for (int it = 0; it < 4; ++it) {                             \
      int r = it * 64 + wid * 8 + lr;                                              \
      int ch = lc ^ (r & 7);                                                       \
      glds16(A + (size_t)(m0 + r) * Kdim + (size_t)(t) * 64 + ch * 8,              \
             &Asm[buf][(it * 64 + wid * 8) * 64]);                                 \
    }                                                                              \
    _Pragma("unroll") for (int it = 0; it < NFRAG; ++it) {                         \
      int r = it * 64 + wid * 8 + lr;                                              \
      int ch = lc ^ (r & 7);                                                       \
      glds16(BT + (size_t)(n0 + r) * Kdim + (size_t)(t) * 64 + ch * 8,             \
             &Bsm[buf][(it * 64 + wid * 8) * 64]);                                 \
    }                                                                              \
  }

  int p = 0;
  STAGE(0, 0);
  for (int t = 0; t < NT; ++t) {
    if (t + 1 < NT) {
      STAGE(p ^ 1, t + 1);
      // wait only for buf p's loads (issued last iter); t+1's stay in flight
      if constexpr (NFRAG == 4) asm volatile("s_waitcnt vmcnt(8)" ::: "memory");
      else                      asm volatile("s_waitcnt vmcnt(6)" ::: "memory");
    } else {
      asm volatile("s_waitcnt vmcnt(0)" ::: "memory");
    }
    __builtin_amdgcn_sched_barrier(0);
    __builtin_amdgcn_s_barrier();

    // B fragments once per tile
    bf16x8 bfrag[NFRAG][2];
#pragma unroll
    for (int nf = 0; nf < NFRAG; ++nf)
#pragma unroll
      for (int kk = 0; kk < 2; ++kk) {
        int r = wn * (NFRAG * 16) + nf * 16 + l15;
        int ch = (kk * 4 + l4) ^ (r & 7);
        bfrag[nf][kk] = *(const bf16x8*)&Bsm[p][r * 64 + ch * 8];
      }
#pragma unroll
    for (int half = 0; half < 2; ++half) {
      bf16x8 afr[4][2];
#pragma unroll
      for (int mf4 = 0; mf4 < 4; ++mf4)
#pragma unroll
        for (int kk = 0; kk < 2; ++kk) {
          int r = wm * 128 + half * 64 + mf4 * 16 + l15;
          int ch = (kk * 4 + l4) ^ (r & 7);
          afr[mf4][kk] = *(const bf16x8*)&Asm[p][r * 64 + ch * 8];
        }
      __builtin_amdgcn_s_setprio(1);
#pragma unroll
      for (int mf4 = 0; mf4 < 4; ++mf4)
#pragma unroll
        for (int nf = 0; nf < NFRAG; ++nf)
#pragma unroll
          for (int kk = 0; kk < 2; ++kk)
            acc[half * 4 + mf4][nf] = __builtin_amdgcn_mfma_f32_16x16x32_bf16(
                afr[mf4][kk], bfrag[nf][kk], acc[half * 4 + mf4][nf], 0, 0, 0);
      __builtin_amdgcn_s_setprio(0);
    }
    __builtin_amdgcn_s_barrier();  // all waves done reading buf p before it is restaged
    p ^= 1;
  }
#undef STAGE

  // epilogue
#pragma unroll
  for (int mf = 0; mf < 8; ++mf)
#pragma unroll
    for (int nf = 0; nf < NFRAG; ++nf) {
      int c = n0 + wn * (NFRAG * 16) + nf * 16 + l15;
      float bv = bias[c];
      int r0 = m0 + wm * 128 + mf * 16 + l4 * 4;
#pragma unroll
      for (int r = 0; r < 4; ++r) {
        float val = acc[mf][nf][r] + bv;
        if (DO_RELU) val = fmaxf(val, 0.f);
        C[(size_t)(r0 + r) * Ndim + c] = (bf16)val;
      }
    }
}

// ---------------- flash attention, swapped-operand 32x32 MFMA (R7-verified) ----------------
__global__ __launch_bounds__(256) void k_attn(const bf16* __restrict__ q,
                                              const bf16* __restrict__ k,
                                              const bf16* __restrict__ vT,
                                              const int* __restrict__ mask,
                                              bf16* __restrict__ ctx, int qs) {
  __shared__ __align__(128) bf16 Kt[2][64 * 64];
  __shared__ __align__(128) bf16 Vt[2][64 * 64];
  __shared__ float Mb[Sn];
  const int tid = threadIdx.x, wid = tid >> 6, lane = tid & 63;
  const int q31 = lane & 31, hi = lane >> 5;

  int lin = blockIdx.y * gridDim.x + blockIdx.x;  // 1024 blocks
  lin = (lin & 7) * 128 + (lin >> 3);
  const int qblk = lin & 15, bh = lin >> 4;
  const int b = bh >> 4, h = bh & 15;
  const int q0 = qblk * 128 + wid * 32;

  for (int i = tid; i < Sn; i += 256)
    Mb[i] = mask[b * Sn + i] ? 0.f : -1.44269504e9f;

  bf16x8 qf[4];
#pragma unroll
  for (int t = 0; t < 4; ++t)
    qf[t] = *(const bf16x8*)(q + (size_t)(b * Sn + q0 + q31) * qs + h * 64 +
                             t * 16 + hi * 8);

  f32x16 o[2];
  o[0] = {}; o[1] = {};
  float mr = -INFINITY, lr = 0.f;

  const int lrow = lane >> 3;
  const int lch0 = lane & 7;

  for (int kb = 0; kb < Sn / 64; ++kb) {
    const int cur = kb & 1;
    if (kb == 0) {
#pragma unroll
      for (int s = 0; s < 2; ++s) {
        int row = (wid + 4 * s) * 8 + lrow;
        int ch = lch0 ^ (lrow ^ ((wid + 4 * s) & 3));
        glds16(k + (size_t)(b * Sn + row) * qs + h * 64 + ch * 8,
               &Kt[0][(wid + 4 * s) * 512]);
        glds16(vT + ((size_t)bh * 64 + row) * Sn + ch * 8,
               &Vt[0][(wid + 4 * s) * 512]);
      }
      __syncthreads();
    }
    if (kb + 1 < Sn / 64) {
#pragma unroll
      for (int s = 0; s < 2; ++s) {
        int row = (wid + 4 * s) * 8 + lrow;
        int ch = lch0 ^ (lrow ^ ((wid + 4 * s) & 3));
        glds16(k + (size_t)(b * Sn + (kb + 1) * 64 + row) * qs + h * 64 + ch * 8,
               &Kt[cur ^ 1][(wid + 4 * s) * 512]);
        glds16(vT + ((size_t)bh * 64 + row) * Sn + (kb + 1) * 64 + ch * 8,
               &Vt[cur ^ 1][(wid + 4 * s) * 512]);
      }
    }

    // S^T = K . Q^T with C initialized to the additive mask bias
    f32x16 sc[2];
#pragma unroll
    for (int kf = 0; kf < 2; ++kf)
#pragma unroll
      for (int rg = 0; rg < 4; ++rg) {
        f32x4 mb4 = *(const f32x4*)&Mb[kb * 64 + kf * 32 + rg * 8 + 4 * hi];
#pragma unroll
        for (int j = 0; j < 4; ++j) sc[kf][rg * 4 + j] = mb4[j];
      }
#pragma unroll
    for (int t = 0; t < 4; ++t) {
#pragma unroll
      for (int kf = 0; kf < 2; ++kf) {
        int row = kf * 32 + q31;
        int ch = (t * 2 + hi) ^ ((row & 7) ^ ((row >> 3) & 3));
        bf16x8 kfr = *(const bf16x8*)&Kt[cur][row * 64 + ch * 8];
        sc[kf] = __builtin_amdgcn_mfma_f32_32x32x16_bf16(kfr, qf[t], sc[kf], 0, 0, 0);
      }
    }

    // row max: pairwise tree + half exchange
    float rmax = fmaxf(sc[0][0], sc[0][1]);
#pragma unroll
    for (int i = 2; i < 16; i += 2)
      rmax = fmaxf(fmaxf(rmax, sc[0][i]), sc[0][i + 1]);
#pragma unroll
    for (int i = 0; i < 16; i += 2)
      rmax = fmaxf(fmaxf(rmax, sc[1][i]), sc[1][i + 1]);
    rmax = fmaxf(rmax, __shfl_xor(rmax, 32));

    if (!__all(rmax <= mr + 8.f)) {
      float mnew = fmaxf(mr, rmax);
      float psc = exp2fast(mr - mnew);
      mr = mnew;
      lr *= psc;
#pragma unroll
      for (int af = 0; af < 2; ++af)
#pragma unroll
        for (int i = 0; i < 16; ++i) o[af][i] *= psc;
    }

    float psum = 0.f;
#pragma unroll
    for (int kf = 0; kf < 2; ++kf)
#pragma unroll
      for (int i = 0; i < 16; ++i) {
        float p = exp2fast(sc[kf][i] - mr);
        sc[kf][i] = p;
        psum += p;
      }
    psum += __shfl_xor(psum, 32);
    lr += psum;

#pragma unroll
    for (int ks = 0; ks < 4; ++ks) {
      const int kf = ks >> 1, R = (ks & 1) * 8;
      unsigned int a0 = pkbf16(sc[kf][R + 0], sc[kf][R + 1]);
      unsigned int a1 = pkbf16(sc[kf][R + 2], sc[kf][R + 3]);
      unsigned int b0 = pkbf16(sc[kf][R + 4], sc[kf][R + 5]);
      unsigned int b1 = pkbf16(sc[kf][R + 6], sc[kf][R + 7]);
      unsigned int sxa0 = __shfl_xor(a0, 32), sxa1 = __shfl_xor(a1, 32);
      unsigned int sxb0 = __shfl_xor(b0, 32), sxb1 = __shfl_xor(b1, 32);
      union { unsigned int w[4]; bf16x8 v; } pfu;
      pfu.w[0] = hi ? sxb0 : a0;
      pfu.w[1] = hi ? sxb1 : a1;
      pfu.w[2] = hi ? b0 : sxa0;
      pfu.w[3] = hi ? b1 : sxa1;
#pragma unroll
      for (int af = 0; af < 2; ++af) {
        int row = af * 32 + q31;
        int ch = (ks * 2 + hi) ^ ((row & 7) ^ ((row >> 3) & 3));
        bf16x8 vfr = *(const bf16x8*)&Vt[cur][row * 64 + ch * 8];
        o[af] = __builtin_amdgcn_mfma_f32_32x32x16_bf16(vfr, pfu.v, o[af], 0, 0, 0);
      }
    }
    __syncthreads();
  }

  float inv = 1.f / lr;
  const size_t cbase = (size_t)(b * Sn + q0 + q31) * Dn + h * 64;
#pragma unroll
  for (int af = 0; af < 2; ++af)
#pragma unroll
    for (int rg = 0; rg < 4; ++rg) {
      bf16x4 ov;
#pragma unroll
      for (int j = 0; j < 4; ++j) ov[j] = (bf16)(o[af][rg * 4 + j] * inv);
      *(bf16x4*)(ctx + cbase + af * 32 + rg * 8 + 4 * hi) = ov;
    }
}

// ---------------- residual + LayerNorm (ddof=1, /(std+eps)) ----------------
template <int XF32, int OUTF32>
__global__ __launch_bounds__(256) void k_ln(const void* __restrict__ xp,
                                            const bf16* __restrict__ res,
                                            const float* __restrict__ gamma,
                                            const float* __restrict__ beta,
                                            void* __restrict__ yout) {
  const int row = blockIdx.x, t = threadIdx.x;
  const size_t base = (size_t)row * Dn + t * 4;
  f32x4 a;
  if constexpr (XF32) {
    a = *(const f32x4*)((const float*)xp + base);
  } else {
    bf16x4 x4 = *(const bf16x4*)((const bf16*)xp + base);
#pragma unroll
    for (int j = 0; j < 4; ++j) a[j] = (float)x4[j];
  }
  bf16x4 rb = *(const bf16x4*)(res + base);
  f32x4 vv;
#pragma unroll
  for (int j = 0; j < 4; ++j) vv[j] = a[j] + (float)rb[j];

  float s = vv[0] + vv[1] + vv[2] + vv[3];
#pragma unroll
  for (int off = 32; off; off >>= 1) s += __shfl_xor(s, off);
  __shared__ float red1[4], red2[4];
  if ((t & 63) == 0) red1[t >> 6] = s;
  __syncthreads();
  float mean = (red1[0] + red1[1] + red1[2] + red1[3]) * (1.f / 1024.f);

  float d[4], s2 = 0.f;
#pragma unroll
  for (int j = 0; j < 4; ++j) { d[j] = vv[j] - mean; s2 += d[j] * d[j]; }
#pragma unroll
  for (int off = 32; off; off >>= 1) s2 += __shfl_xor(s2, off);
  if ((t & 63) == 0) red2[t >> 6] = s2;
  __syncthreads();
  float var = (red2[0] + red2[1] + red2[2] + red2[3]) * (1.f / 1023.f);
  float inv = 1.f / (sqrtf(var) + 1e-6f);

  f32x4 g = *(const f32x4*)(gamma + t * 4);
  f32x4 bt = *(const f32x4*)(beta + t * 4);
#pragma unroll
  for (int j = 0; j < 4; ++j) d[j] = g[j] * d[j] * inv + bt[j];
  if constexpr (OUTF32) {
    f32x4 outv = {d[0], d[1], d[2], d[3]};
    *(f32x4*)((float*)yout + base) = outv;
  } else {
    bf16x4 outb;
#pragma unroll
    for (int j = 0; j < 4; ++j) outb[j] = (bf16)d[j];
    *(bf16x4*)((bf16*)yout + base) = outb;
  }
}

// ---------------- host launcher ----------------
extern "C" void kernel_launch(void* const* d_in, const int* in_sizes, int n_in,
                              void* d_out, int out_size, void* d_ws, size_t ws_size,
                              hipStream_t stream) {
  const float* x   = (const float*)d_in[0];
  const int*   msk = (const int*)d_in[1];
  const float* Wq  = (const float*)d_in[2];
  const float* bq  = (const float*)d_in[3];
  const float* Wk  = (const float*)d_in[4];
  const float* bk  = (const float*)d_in[5];
  const float* Wv  = (const float*)d_in[6];
  const float* bv  = (const float*)d_in[7];
  const float* Wo  = (const float*)d_in[8];
  const float* bo  = (const float*)d_in[9];
  const float* W1  = (const float*)d_in[10];
  const float* b1  = (const float*)d_in[11];
  const float* W2  = (const float*)d_in[12];
  const float* b2  = (const float*)d_in[13];
  const float* g1  = (const float*)d_in[14];
  const float* be1 = (const float*)d_in[15];
  const float* g2  = (const float*)d_in[16];
  const float* be2 = (const float*)d_in[17];
  float* out = (float*)d_out;

  char* w = (char*)d_ws;
  size_t off = 0;
  auto alloc = [&](size_t bytes) { void* p = w + off; off += (bytes + 255) & ~(size_t)255; return p; };
  bf16* xb    = (bf16*)alloc((size_t)Mn * Dn * 2);        // 16MB; dead after QKV -> vT overlay
  bf16* wqkvT = (bf16*)alloc((size_t)QKVS * Dn * 2);      // 6MB
  bf16* woT   = (bf16*)alloc((size_t)Dn * Dn * 2);        // 2MB
  bf16* w1T   = (bf16*)alloc((size_t)Dn * DFFn * 2);      // 8MB
  bf16* w2T   = (bf16*)alloc((size_t)DFFn * Dn * 2);      // 8MB
  float* bqkv = (float*)alloc((size_t)QKVS * 4);
  bf16* qkv   = (bf16*)alloc((size_t)Mn * QKVS * 2);      // 48MB; dead after attn -> hh
  bf16* ctx   = (bf16*)alloc((size_t)Mn * Dn * 2);        // 16MB; dead after Wo
  bf16* attnb = (bf16*)alloc((size_t)Mn * Dn * 2);        // 16MB; Wo out, dead after LN1
  bf16* yb    = (bf16*)alloc((size_t)Mn * Dn * 2);        // 16MB (residual stream, bf16)
  (void)ws_size; (void)in_sizes; (void)n_in; (void)out_size;
  // overlays (regions dead by the time these are written):
  bf16* vT = xb;          // attn V^T; xb dead after QKV GEMM
  bf16* hh = qkv;         // FF1 out 64MB: spans qkv(48) + ctx(16), both dead
  bf16* ff = xb;          // FF2 out 16MB: xb/vT dead after attn

  // 1. pack x, transpose weights (Wq pre-scaled for exp2-domain softmax), biases
  k_cvt_bf16<<<(Mn * Dn) / 2048, 256, 0, stream>>>(x, xb);
  dim3 tb(32, 8);
  k_transpose_bf16<<<dim3(32, 32), tb, 0, stream>>>(Wq, wqkvT, Dn, Dn, LOG2E_DIV8);
  k_transpose_bf16<<<dim3(32, 32), tb, 0, stream>>>(Wk, wqkvT + (size_t)1024 * Dn, Dn, Dn, 1.f);
  k_transpose_bf16<<<dim3(32, 32), tb, 0, stream>>>(Wv, wqkvT + (size_t)2048 * Dn, Dn, Dn, 1.f);
  k_transpose_bf16<<<dim3(32, 32), tb, 0, stream>>>(Wo, woT, Dn, Dn, 1.f);
  k_transpose_bf16<<<dim3(128, 32), tb, 0, stream>>>(W1, w1T, Dn, DFFn, 1.f);
  k_transpose_bf16<<<dim3(32, 128), tb, 0, stream>>>(W2, w2T, DFFn, Dn, 1.f);
  k_bias3<<<QKVS / 256, 256, 0, stream>>>(bq, bk, bv, bqkv);

  // 2. fused QKV projection: qkv[8192][3072]
  k_gemm256<4, 0><<<dim3(QKVS / 256, Mn / 256), 512, 0, stream>>>(xb, wqkvT, bqkv, qkv, QKVS, Dn);

  // 3. V transpose + flash attention
  k_vt<<<dim3(Sn / 64, Bn * Hn), 256, 0, stream>>>(qkv + 2048, vT, QKVS);
  k_attn<<<dim3(Sn / 128, Bn * Hn), 256, 0, stream>>>(qkv, qkv + 1024, vT, msk, ctx, QKVS);

  // 4. output projection (bf16 out)
  k_gemm256<2, 0><<<dim3(Dn / 128, Mn / 256), 512, 0, stream>>>(ctx, woT, bo, attnb, Dn, Dn);

  // 5. LN1: yb = LN(x + attnb), bf16 out
  k_ln<1, 0><<<Mn, 256, 0, stream>>>(x, attnb, g1, be1, yb);

  // 6. FF1 (relu)
  k_gemm256<4, 1><<<dim3(DFFn / 256, Mn / 256), 512, 0, stream>>>(yb, w1T, b1, hh, DFFn, Dn);

  // 7. FF2
  k_gemm256<2, 0><<<dim3(Dn / 128, Mn / 256), 512, 0, stream>>>(hh, w2T, b2, ff, Dn, DFFn);

  // 8. LN2: out = LN(yb + ff), f32 out
  k_ln<0, 1><<<Mn, 256, 0, stream>>>(yb, ff, g2, be2, out);
}

// Round 9
// 414.027 us; speedup vs baseline: 1.3918x; 1.1046x over previous
//
#include <hip/hip_runtime.h>

// ---------------- problem constants ----------------
#define Bn 4
#define Sn 2048
#define Dn 1024
#define Hn 16
#define DKn 64
#define DFFn 4096
#define Mn (Bn * Sn) // 8192
#define QKVS 3072    // fused QKV row stride

typedef __bf16 bf16;
typedef __attribute__((ext_vector_type(8))) __bf16 bf16x8;
typedef __attribute__((ext_vector_type(4))) __bf16 bf16x4;
typedef __attribute__((ext_vector_type(8))) unsigned short u16x8;
typedef __attribute__((ext_vector_type(4))) float f32x4;
typedef __attribute__((ext_vector_type(16))) float f32x16;

#define LOG2E_DIV8 0.18033688011112042f  // 0.125 * log2(e)

__device__ __forceinline__ float exp2fast(float x) {
  return __builtin_amdgcn_exp2f(x);
}

// async global->LDS, 16B per lane; LDS dest = wave-uniform base + lane*16
__device__ __forceinline__ void glds16(const bf16* g, bf16* l) {
  __builtin_amdgcn_global_load_lds((const __attribute__((address_space(1))) void*)g,
                                   (__attribute__((address_space(3))) void*)l, 16, 0, 0);
}

__device__ __forceinline__ unsigned int pkbf16(float a, float b) {
  union { __bf16 h[2]; unsigned int u; } x;
  x.h[0] = (__bf16)a; x.h[1] = (__bf16)b;
  return x.u;
}

// ---------------- f32 -> bf16 pack ----------------
__global__ __launch_bounds__(256) void k_cvt_bf16(const float* __restrict__ in,
                                                  bf16* __restrict__ out) {
  size_t i = ((size_t)blockIdx.x * 256 + threadIdx.x) * 8;
  f32x4 a = *(const f32x4*)(in + i);
  f32x4 b = *(const f32x4*)(in + i + 4);
  bf16x8 o;
#pragma unroll
  for (int j = 0; j < 4; ++j) { o[j] = (bf16)a[j]; o[j + 4] = (bf16)b[j]; }
  *(bf16x8*)(out + i) = o;
}

// ---------------- merged prep: all weight transposes + fused-QKV bias ----------------
// ids 0..1023 Wq, 1024..2047 Wk, 2048..3071 Wv, 3072..4095 Wo,
// 4096..8191 W1 (128x32), 8192..12287 W2 (32x128), 12288..12299 bias concat.
__global__ __launch_bounds__(256) void k_prep(const float* __restrict__ Wq,
                                              const float* __restrict__ Wk,
                                              const float* __restrict__ Wv,
                                              const float* __restrict__ Wo,
                                              const float* __restrict__ W1,
                                              const float* __restrict__ W2,
                                              const float* __restrict__ bq,
                                              const float* __restrict__ bk,
                                              const float* __restrict__ bv,
                                              bf16* __restrict__ wqkvT,
                                              bf16* __restrict__ woT,
                                              bf16* __restrict__ w1T,
                                              bf16* __restrict__ w2T,
                                              float* __restrict__ bqkv) {
  __shared__ float tile[32][33];
  const int id = blockIdx.x, t = threadIdx.x;
  if (id >= 12288) {  // bias concat
    int j = (id - 12288) * 256 + t;
    float v = (j < 1024) ? bq[j] * LOG2E_DIV8
            : (j < 2048) ? bk[j - 1024] : bv[j - 2048];
    bqkv[j] = v;
    return;
  }
  const float* in;
  bf16* out;
  int K, N, bx, by;
  float scale = 1.f;
  if (id < 4096) {
    int z = id >> 10, local = id & 1023;
    bx = local & 31; by = local >> 5;
    K = Dn; N = Dn;
    if (z == 0)      { in = Wq; out = wqkvT; scale = LOG2E_DIV8; }
    else if (z == 1) { in = Wk; out = wqkvT + (size_t)1024 * Dn; }
    else if (z == 2) { in = Wv; out = wqkvT + (size_t)2048 * Dn; }
    else             { in = Wo; out = woT; }
  } else if (id < 8192) {
    int local = id - 4096;
    bx = local & 127; by = local >> 7;
    K = Dn; N = DFFn; in = W1; out = w1T;
  } else {
    int local = id - 8192;
    bx = local & 31; by = local >> 5;
    K = DFFn; N = Dn; in = W2; out = w2T;
  }
  const int n0 = bx * 32, k0 = by * 32;
  const int tx = t & 31, ty = t >> 5;
#pragma unroll
  for (int j = ty; j < 32; j += 8)
    tile[j][tx] = in[(size_t)(k0 + j) * N + n0 + tx];
  __syncthreads();
#pragma unroll
  for (int j = ty; j < 32; j += 8)
    out[(size_t)(n0 + j) * K + k0 + tx] = (bf16)(tile[tx][j] * scale);
}

// ---------------- V transpose: v[b*S+s][h*64+dk] (stride vs) -> vT[(bh*64+dk)][s] ----------------
__global__ __launch_bounds__(256) void k_vt(const bf16* __restrict__ v,
                                            bf16* __restrict__ vT, int vs) {
  __shared__ bf16 T[64][72];
  const int t = threadIdx.x;
  const int s0 = blockIdx.x * 64;
  const int bh = blockIdx.y, b = bh >> 4, h = bh & 15;
#pragma unroll
  for (int it = 0; it < 2; ++it) {
    int r = (t >> 3) + it * 32;
    int c = t & 7;
    u16x8 val = *(const u16x8*)(v + (size_t)(b * Sn + s0 + r) * vs + h * 64 + c * 8);
    *(u16x8*)&T[r][c * 8] = val;
  }
  __syncthreads();
#pragma unroll
  for (int it = 0; it < 2; ++it) {
    int d = (t >> 3) + it * 32;
    int cs = t & 7;
    bf16x8 o;
#pragma unroll
    for (int j = 0; j < 8; ++j) o[j] = T[cs * 8 + j][d];
    *(bf16x8*)(vT + ((size_t)bh * 64 + d) * Sn + s0 + cs * 8) = o;
  }
}

// ---------------- 256-row MFMA GEMM, 8 waves, counted-vmcnt pipeline (R5-verified) ----------------
template <int NFRAG, int DO_RELU>
__global__ __launch_bounds__(512, 2) void k_gemm256(const bf16* __restrict__ A,
                                                    const bf16* __restrict__ BT,
                                                    const float* __restrict__ bias,
                                                    bf16* __restrict__ C,
                                                    int Ndim, int Kdim) {
  __shared__ __align__(128) bf16 Asm[2][256 * 64];
  __shared__ __align__(128) bf16 Bsm[2][NFRAG * 64 * 64];
  const int tid = threadIdx.x;
  const int wid = tid >> 6, lane = tid & 63;
  const int l15 = lane & 15, l4 = lane >> 4;
  const int wm = wid >> 2, wn = wid & 3;

  // XCD-chunked swizzle (all grids here have nwg % 8 == 0)
  const int gx = gridDim.x;
  int lin = blockIdx.y * gx + blockIdx.x;
  const int nwg = gx * gridDim.y;
  lin = (lin & 7) * (nwg >> 3) + (lin >> 3);
  const int m0 = (lin / gx) * 256;
  const int n0 = (lin % gx) * (NFRAG * 64);

  f32x4 acc[8][NFRAG];
#pragma unroll
  for (int mf = 0; mf < 8; ++mf)
#pragma unroll
    for (int nf = 0; nf < NFRAG; ++nf) acc[mf][nf] = f32x4{0.f, 0.f, 0.f, 0.f};

  const int lr = lane >> 3, lc = lane & 7;
  const int NT = Kdim >> 6;

#define STAGE(buf, t)                                                              \
  {                                                                                \
    _Pragma("unroll") for (int it = 0; it < 4; ++it) {                             \
      int r = it * 64 + wid * 8 + lr;                                              \
      int ch = lc ^ (r & 7);                                                       \
      glds16(A + (size_t)(m0 + r) * Kdim + (size_t)(t) * 64 + ch * 8,              \
             &Asm[buf][(it * 64 + wid * 8) * 64]);                                 \
    }                                                                              \
    _Pragma("unroll") for (int it = 0; it < NFRAG; ++it) {                         \
      int r = it * 64 + wid * 8 + lr;                                              \
      int ch = lc ^ (r & 7);                                                       \
      glds16(BT + (size_t)(n0 + r) * Kdim + (size_t)(t) * 64 + ch * 8,             \
             &Bsm[buf][(it * 64 + wid * 8) * 64]);                                 \
    }                                                                              \
  }

  int p = 0;
  STAGE(0, 0);
  for (int t = 0; t < NT; ++t) {
    if (t + 1 < NT) {
      STAGE(p ^ 1, t + 1);
      // wait only for buf p's loads (issued last iter); t+1's stay in flight
      if constexpr (NFRAG == 4) asm volatile("s_waitcnt vmcnt(8)" ::: "memory");
      else                      asm volatile("s_waitcnt vmcnt(6)" ::: "memory");
    } else {
      asm volatile("s_waitcnt vmcnt(0)" ::: "memory");
    }
    __builtin_amdgcn_sched_barrier(0);
    __builtin_amdgcn_s_barrier();

    // B fragments once per tile
    bf16x8 bfrag[NFRAG][2];
#pragma unroll
    for (int nf = 0; nf < NFRAG; ++nf)
#pragma unroll
      for (int kk = 0; kk < 2; ++kk) {
        int r = wn * (NFRAG * 16) + nf * 16 + l15;
        int ch = (kk * 4 + l4) ^ (r & 7);
        bfrag[nf][kk] = *(const bf16x8*)&Bsm[p][r * 64 + ch * 8];
      }
#pragma unroll
    for (int half = 0; half < 2; ++half) {
      bf16x8 afr[4][2];
#pragma unroll
      for (int mf4 = 0; mf4 < 4; ++mf4)
#pragma unroll
        for (int kk = 0; kk < 2; ++kk) {
          int r = wm * 128 + half * 64 + mf4 * 16 + l15;
          int ch = (kk * 4 + l4) ^ (r & 7);
          afr[mf4][kk] = *(const bf16x8*)&Asm[p][r * 64 + ch * 8];
        }
      __builtin_amdgcn_s_setprio(1);
#pragma unroll
      for (int mf4 = 0; mf4 < 4; ++mf4)
#pragma unroll
        for (int nf = 0; nf < NFRAG; ++nf)
#pragma unroll
          for (int kk = 0; kk < 2; ++kk)
            acc[half * 4 + mf4][nf] = __builtin_amdgcn_mfma_f32_16x16x32_bf16(
                afr[mf4][kk], bfrag[nf][kk], acc[half * 4 + mf4][nf], 0, 0, 0);
      __builtin_amdgcn_s_setprio(0);
    }
    __builtin_amdgcn_s_barrier();  // all waves done reading buf p before it is restaged
    p ^= 1;
  }
#undef STAGE

  // epilogue
#pragma unroll
  for (int mf = 0; mf < 8; ++mf)
#pragma unroll
    for (int nf = 0; nf < NFRAG; ++nf) {
      int c = n0 + wn * (NFRAG * 16) + nf * 16 + l15;
      float bv = bias[c];
      int r0 = m0 + wm * 128 + mf * 16 + l4 * 4;
#pragma unroll
      for (int r = 0; r < 4; ++r) {
        float val = acc[mf][nf][r] + bv;
        if (DO_RELU) val = fmaxf(val, 0.f);
        C[(size_t)(r0 + r) * Ndim + c] = (bf16)val;
      }
    }
}

// ---------------- flash attention, swapped-operand 32x32 MFMA, 8 waves/block ----------------
// grid (S/256, B*H) XCD-swizzled, 512 thr. Wave owns 32 q rows; block 256 q rows.
// 40KB LDS -> up to 4 blocks/CU for cross-wave MFMA/VALU overlap.
__global__ __launch_bounds__(512) void k_attn(const bf16* __restrict__ q,
                                              const bf16* __restrict__ k,
                                              const bf16* __restrict__ vT,
                                              const int* __restrict__ mask,
                                              bf16* __restrict__ ctx, int qs) {
  __shared__ __align__(128) bf16 Kt[2][64 * 64];
  __shared__ __align__(128) bf16 Vt[2][64 * 64];
  __shared__ float Mb[Sn];
  const int tid = threadIdx.x, wid = tid >> 6, lane = tid & 63;
  const int q31 = lane & 31, hi = lane >> 5;

  int lin = blockIdx.y * gridDim.x + blockIdx.x;  // 512 blocks
  lin = (lin & 7) * 64 + (lin >> 3);
  const int qblk = lin & 7, bh = lin >> 3;
  const int b = bh >> 4, h = bh & 15;
  const int q0 = qblk * 256 + wid * 32;

  for (int i = tid; i < Sn; i += 512)
    Mb[i] = mask[b * Sn + i] ? 0.f : -1.44269504e9f;

  bf16x8 qf[4];
#pragma unroll
  for (int t = 0; t < 4; ++t)
    qf[t] = *(const bf16x8*)(q + (size_t)(b * Sn + q0 + q31) * qs + h * 64 +
                             t * 16 + hi * 8);

  f32x16 o[2];
  o[0] = {}; o[1] = {};
  float mr = -INFINITY, lr = 0.f;

  // staging: wave wid stages rows [wid*8, wid*8+8) of the 64-row tile
  const int lrow = lane >> 3;
  const int lch0 = lane & 7;
  const int sch = lch0 ^ (lrow ^ (wid & 3));  // pre-swizzled source chunk

  for (int kb = 0; kb < Sn / 64; ++kb) {
    const int cur = kb & 1;
    if (kb == 0) {
      int row = wid * 8 + lrow;
      glds16(k + (size_t)(b * Sn + row) * qs + h * 64 + sch * 8, &Kt[0][wid * 512]);
      glds16(vT + ((size_t)bh * 64 + row) * Sn + sch * 8, &Vt[0][wid * 512]);
      __syncthreads();
    }
    if (kb + 1 < Sn / 64) {
      int row = wid * 8 + lrow;
      glds16(k + (size_t)(b * Sn + (kb + 1) * 64 + row) * qs + h * 64 + sch * 8,
             &Kt[cur ^ 1][wid * 512]);
      glds16(vT + ((size_t)bh * 64 + row) * Sn + (kb + 1) * 64 + sch * 8,
             &Vt[cur ^ 1][wid * 512]);
    }

    // S^T = K . Q^T with C initialized to the additive mask bias
    f32x16 sc[2];
#pragma unroll
    for (int kf = 0; kf < 2; ++kf)
#pragma unroll
      for (int rg = 0; rg < 4; ++rg) {
        f32x4 mb4 = *(const f32x4*)&Mb[kb * 64 + kf * 32 + rg * 8 + 4 * hi];
#pragma unroll
        for (int j = 0; j < 4; ++j) sc[kf][rg * 4 + j] = mb4[j];
      }
#pragma unroll
    for (int t = 0; t < 4; ++t) {
#pragma unroll
      for (int kf = 0; kf < 2; ++kf) {
        int row = kf * 32 + q31;
        int ch = (t * 2 + hi) ^ ((row & 7) ^ ((row >> 3) & 3));
        bf16x8 kfr = *(const bf16x8*)&Kt[cur][row * 64 + ch * 8];
        sc[kf] = __builtin_amdgcn_mfma_f32_32x32x16_bf16(kfr, qf[t], sc[kf], 0, 0, 0);
      }
    }

    // row max: pairwise tree + half exchange
    float rmax = fmaxf(sc[0][0], sc[0][1]);
#pragma unroll
    for (int i = 2; i < 16; i += 2)
      rmax = fmaxf(fmaxf(rmax, sc[0][i]), sc[0][i + 1]);
#pragma unroll
    for (int i = 0; i < 16; i += 2)
      rmax = fmaxf(fmaxf(rmax, sc[1][i]), sc[1][i + 1]);
    rmax = fmaxf(rmax, __shfl_xor(rmax, 32));

    if (!__all(rmax <= mr + 8.f)) {
      float mnew = fmaxf(mr, rmax);
      float psc = exp2fast(mr - mnew);
      mr = mnew;
      lr *= psc;
#pragma unroll
      for (int af = 0; af < 2; ++af)
#pragma unroll
        for (int i = 0; i < 16; ++i) o[af][i] *= psc;
    }

    float psum = 0.f;
#pragma unroll
    for (int kf = 0; kf < 2; ++kf)
#pragma unroll
      for (int i = 0; i < 16; ++i) {
        float p = exp2fast(sc[kf][i] - mr);
        sc[kf][i] = p;
        psum += p;
      }
    psum += __shfl_xor(psum, 32);
    lr += psum;

#pragma unroll
    for (int ks = 0; ks < 4; ++ks) {
      const int kf = ks >> 1, R = (ks & 1) * 8;
      unsigned int a0 = pkbf16(sc[kf][R + 0], sc[kf][R + 1]);
      unsigned int a1 = pkbf16(sc[kf][R + 2], sc[kf][R + 3]);
      unsigned int b0 = pkbf16(sc[kf][R + 4], sc[kf][R + 5]);
      unsigned int b1 = pkbf16(sc[kf][R + 6], sc[kf][R + 7]);
      unsigned int sxa0 = __shfl_xor(a0, 32), sxa1 = __shfl_xor(a1, 32);
      unsigned int sxb0 = __shfl_xor(b0, 32), sxb1 = __shfl_xor(b1, 32);
      union { unsigned int w[4]; bf16x8 v; } pfu;
      pfu.w[0] = hi ? sxb0 : a0;
      pfu.w[1] = hi ? sxb1 : a1;
      pfu.w[2] = hi ? b0 : sxa0;
      pfu.w[3] = hi ? b1 : sxa1;
#pragma unroll
      for (int af = 0; af < 2; ++af) {
        int row = af * 32 + q31;
        int ch = (ks * 2 + hi) ^ ((row & 7) ^ ((row >> 3) & 3));
        bf16x8 vfr = *(const bf16x8*)&Vt[cur][row * 64 + ch * 8];
        o[af] = __builtin_amdgcn_mfma_f32_32x32x16_bf16(vfr, pfu.v, o[af], 0, 0, 0);
      }
    }
    __syncthreads();
  }

  float inv = 1.f / lr;
  const size_t cbase = (size_t)(b * Sn + q0 + q31) * Dn + h * 64;
#pragma unroll
  for (int af = 0; af < 2; ++af)
#pragma unroll
    for (int rg = 0; rg < 4; ++rg) {
      bf16x4 ov;
#pragma unroll
      for (int j = 0; j < 4; ++j) ov[j] = (bf16)(o[af][rg * 4 + j] * inv);
      *(bf16x4*)(ctx + cbase + af * 32 + rg * 8 + 4 * hi) = ov;
    }
}

// ---------------- residual + LayerNorm (ddof=1, /(std+eps)) ----------------
template <int XF32, int OUTF32>
__global__ __launch_bounds__(256) void k_ln(const void* __restrict__ xp,
                                            const bf16* __restrict__ res,
                                            const float* __restrict__ gamma,
                                            const float* __restrict__ beta,
                                            void* __restrict__ yout) {
  const int row = blockIdx.x, t = threadIdx.x;
  const size_t base = (size_t)row * Dn + t * 4;
  f32x4 a;
  if constexpr (XF32) {
    a = *(const f32x4*)((const float*)xp + base);
  } else {
    bf16x4 x4 = *(const bf16x4*)((const bf16*)xp + base);
#pragma unroll
    for (int j = 0; j < 4; ++j) a[j] = (float)x4[j];
  }
  bf16x4 rb = *(const bf16x4*)(res + base);
  f32x4 vv;
#pragma unroll
  for (int j = 0; j < 4; ++j) vv[j] = a[j] + (float)rb[j];

  float s = vv[0] + vv[1] + vv[2] + vv[3];
#pragma unroll
  for (int off = 32; off; off >>= 1) s += __shfl_xor(s, off);
  __shared__ float red1[4], red2[4];
  if ((t & 63) == 0) red1[t >> 6] = s;
  __syncthreads();
  float mean = (red1[0] + red1[1] + red1[2] + red1[3]) * (1.f / 1024.f);

  float d[4], s2 = 0.f;
#pragma unroll
  for (int j = 0; j < 4; ++j) { d[j] = vv[j] - mean; s2 += d[j] * d[j]; }
#pragma unroll
  for (int off = 32; off; off >>= 1) s2 += __shfl_xor(s2, off);
  if ((t & 63) == 0) red2[t >> 6] = s2;
  __syncthreads();
  float var = (red2[0] + red2[1] + red2[2] + red2[3]) * (1.f / 1023.f);
  float inv = 1.f / (sqrtf(var) + 1e-6f);

  f32x4 g = *(const f32x4*)(gamma + t * 4);
  f32x4 bt = *(const f32x4*)(beta + t * 4);
#pragma unroll
  for (int j = 0; j < 4; ++j) d[j] = g[j] * d[j] * inv + bt[j];
  if constexpr (OUTF32) {
    f32x4 outv = {d[0], d[1], d[2], d[3]};
    *(f32x4*)((float*)yout + base) = outv;
  } else {
    bf16x4 outb;
#pragma unroll
    for (int j = 0; j < 4; ++j) outb[j] = (bf16)d[j];
    *(bf16x4*)((bf16*)yout + base) = outb;
  }
}

// ---------------- host launcher ----------------
extern "C" void kernel_launch(void* const* d_in, const int* in_sizes, int n_in,
                              void* d_out, int out_size, void* d_ws, size_t ws_size,
                              hipStream_t stream) {
  const float* x   = (const float*)d_in[0];
  const int*   msk = (const int*)d_in[1];
  const float* Wq  = (const float*)d_in[2];
  const float* bq  = (const float*)d_in[3];
  const float* Wk  = (const float*)d_in[4];
  const float* bk  = (const float*)d_in[5];
  const float* Wv  = (const float*)d_in[6];
  const float* bv  = (const float*)d_in[7];
  const float* Wo  = (const float*)d_in[8];
  const float* bo  = (const float*)d_in[9];
  const float* W1  = (const float*)d_in[10];
  const float* b1  = (const float*)d_in[11];
  const float* W2  = (const float*)d_in[12];
  const float* b2  = (const float*)d_in[13];
  const float* g1  = (const float*)d_in[14];
  const float* be1 = (const float*)d_in[15];
  const float* g2  = (const float*)d_in[16];
  const float* be2 = (const float*)d_in[17];
  float* out = (float*)d_out;

  char* w = (char*)d_ws;
  size_t off = 0;
  auto alloc = [&](size_t bytes) { void* p = w + off; off += (bytes + 255) & ~(size_t)255; return p; };
  bf16* xb    = (bf16*)alloc((size_t)Mn * Dn * 2);        // 16MB; dead after QKV -> vT overlay
  bf16* wqkvT = (bf16*)alloc((size_t)QKVS * Dn * 2);      // 6MB
  bf16* woT   = (bf16*)alloc((size_t)Dn * Dn * 2);        // 2MB
  bf16* w1T   = (bf16*)alloc((size_t)Dn * DFFn * 2);      // 8MB
  bf16* w2T   = (bf16*)alloc((size_t)DFFn * Dn * 2);      // 8MB
  float* bqkv = (float*)alloc((size_t)QKVS * 4);
  bf16* qkv   = (bf16*)alloc((size_t)Mn * QKVS * 2);      // 48MB; dead after attn -> hh
  bf16* ctx   = (bf16*)alloc((size_t)Mn * Dn * 2);        // 16MB; dead after Wo
  bf16* attnb = (bf16*)alloc((size_t)Mn * Dn * 2);        // 16MB; Wo out, dead after LN1
  bf16* yb    = (bf16*)alloc((size_t)Mn * Dn * 2);        // 16MB (residual stream, bf16)
  (void)ws_size; (void)in_sizes; (void)n_in; (void)out_size;
  // overlays (regions dead by the time these are written):
  bf16* vT = xb;          // attn V^T; xb dead after QKV GEMM
  bf16* hh = qkv;         // FF1 out 64MB: spans qkv(48) + ctx(16), both dead
  bf16* ff = xb;          // FF2 out 16MB: xb/vT dead after attn

  // 1. pack x; merged weight transposes + bias concat
  k_cvt_bf16<<<(Mn * Dn) / 2048, 256, 0, stream>>>(x, xb);
  k_prep<<<12300, 256, 0, stream>>>(Wq, Wk, Wv, Wo, W1, W2, bq, bk, bv,
                                    wqkvT, woT, w1T, w2T, bqkv);

  // 2. fused QKV projection: qkv[8192][3072]
  k_gemm256<4, 0><<<dim3(QKVS / 256, Mn / 256), 512, 0, stream>>>(xb, wqkvT, bqkv, qkv, QKVS, Dn);

  // 3. V transpose + flash attention (8-wave blocks)
  k_vt<<<dim3(Sn / 64, Bn * Hn), 256, 0, stream>>>(qkv + 2048, vT, QKVS);
  k_attn<<<dim3(Sn / 256, Bn * Hn), 512, 0, stream>>>(qkv, qkv + 1024, vT, msk, ctx, QKVS);

  // 4. output projection (bf16 out)
  k_gemm256<2, 0><<<dim3(Dn / 128, Mn / 256), 512, 0, stream>>>(ctx, woT, bo, attnb, Dn, Dn);

  // 5. LN1: yb = LN(x + attnb), bf16 out
  k_ln<1, 0><<<Mn, 256, 0, stream>>>(x, attnb, g1, be1, yb);

  // 6. FF1 (relu)
  k_gemm256<4, 1><<<dim3(DFFn / 256, Mn / 256), 512, 0, stream>>>(yb, w1T, b1, hh, DFFn, Dn);

  // 7. FF2
  k_gemm256<2, 0><<<dim3(Dn / 128, Mn / 256), 512, 0, stream>>>(hh, w2T, b2, ff, Dn, DFFn);

  // 8. LN2: out = LN(yb + ff), f32 out
  k_ln<0, 1><<<Mn, 256, 0, stream>>>(yb, ff, g2, be2, out);
}